// Round 3
// baseline (1206.753 us; speedup 1.0000x reference)
//
#include <hip/hip_runtime.h>

#define D       128
#define NNODES  50000
#define NEDGES  600000
#define TE      64
#define BLK     256
#define LN_EPS  1e-5f

typedef float  fx4    __attribute__((ext_vector_type(4)));
typedef float  f32x4  __attribute__((ext_vector_type(4)));
typedef __bf16 bf16x4 __attribute__((ext_vector_type(4)));
typedef __bf16 bf16x8 __attribute__((ext_vector_type(8)));

// ---- d_ws layout ----
// bf16 weights first, then CSR int arrays
#define EW1T_OFF 0                         // [128][384]
#define EW2T_OFF (128 * 384)               // [128][128]
#define NW1T_OFF (EW2T_OFF + 128 * 128)    // [128][256]
#define NW2T_OFF (NW1T_OFF + 128 * 256)    // [128][128]
#define WS_ELEMS (NW2T_OFF + 128 * 128)    // 114688 bf16
#define W_BYTES  (WS_ELEMS * 2)            // 229376
// int arrays (byte offsets from ws base)
#define COUNTS_OFF  (W_BYTES)
#define OFFS_OFF    (COUNTS_OFF + 4 * NNODES)
#define CURS_OFF    (OFFS_OFF   + 4 * (NNODES + 1))
#define ELIST_OFF   (CURS_OFF   + 4 * NNODES)
#define WS_NEED     (ELIST_OFF  + 4 * NEDGES)

__device__ __forceinline__ float silu_f(float z) {
    return z * (1.0f / (1.0f + __expf(-z)));
}

// ---------------------------------------------------------------------------
// Weight prep: transpose + f32->bf16.  out[n][k] = in[k][n]  (N=128 always)
// ---------------------------------------------------------------------------
__global__ __launch_bounds__(256) void prep_weights(
    const float* __restrict__ eW1, const float* __restrict__ eW2,
    const float* __restrict__ nW1, const float* __restrict__ nW2,
    __bf16* __restrict__ ws)
{
    int idx = blockIdx.x * 256 + threadIdx.x;
    if (idx >= WS_ELEMS) return;
    const float* src;
    int K, local;
    if (idx < EW2T_OFF)      { src = eW1; K = 384; local = idx; }
    else if (idx < NW1T_OFF) { src = eW2; K = 128; local = idx - EW2T_OFF; }
    else if (idx < NW2T_OFF) { src = nW1; K = 256; local = idx - NW1T_OFF; }
    else                     { src = nW2; K = 128; local = idx - NW2T_OFF; }
    int n = local / K, k = local % K;
    ws[idx] = (__bf16)src[(size_t)k * D + n];
}

// ---------------------------------------------------------------------------
// CSR build: histogram -> exclusive scan -> scatter
// ---------------------------------------------------------------------------
__global__ __launch_bounds__(256) void hist_kernel(
    const int* __restrict__ edge_index, int* __restrict__ counts)
{
    int i = blockIdx.x * 256 + threadIdx.x;
    if (i < NEDGES) atomicAdd(&counts[edge_index[NEDGES + i]], 1);
}

__global__ __launch_bounds__(256) void scan_kernel(
    const int* __restrict__ counts, int* __restrict__ offs, int* __restrict__ curs)
{
    __shared__ int sh[256];
    const int t = threadIdx.x;
    const int STRIP = (NNODES + 255) / 256;   // 196
    const int base = t * STRIP;

    int tsum = 0;
    for (int i = 0; i < STRIP; ++i) {
        int idx = base + i;
        if (idx < NNODES) tsum += counts[idx];
    }
    sh[t] = tsum;
    __syncthreads();
    for (int off = 1; off < 256; off <<= 1) {
        int add = (t >= off) ? sh[t - off] : 0;
        __syncthreads();
        sh[t] += add;
        __syncthreads();
    }
    int run = (t > 0) ? sh[t - 1] : 0;   // exclusive prefix of this strip
    for (int i = 0; i < STRIP; ++i) {
        int idx = base + i;
        if (idx < NNODES) {
            offs[idx] = run;
            curs[idx] = run;
            run += counts[idx];
        }
    }
    if (t == 255) offs[NNODES] = run;
}

__global__ __launch_bounds__(256) void scatter_kernel(
    const int* __restrict__ edge_index, int* __restrict__ curs,
    int* __restrict__ elist)
{
    int i = blockIdx.x * 256 + threadIdx.x;
    if (i < NEDGES) {
        int pos = atomicAdd(&curs[edge_index[NEDGES + i]], 1);
        elist[pos] = i;
    }
}

// ---------------------------------------------------------------------------
// Edge kernel (bf16 MFMA): 64 edges/block, 4 waves, 16 rows each.
// ---------------------------------------------------------------------------
template<bool ATOMIC>
__global__ __launch_bounds__(BLK) void edge_kernel(
    const float* __restrict__ x,
    const float* __restrict__ edge_attr,
    const int*   __restrict__ edge_index,
    const __bf16* __restrict__ W1T,   // [128][384]
    const float* __restrict__ b1,
    const __bf16* __restrict__ W2T,   // [128][128]
    const float* __restrict__ b2,
    const float* __restrict__ lng, const float* __restrict__ lnb,
    float* __restrict__ edges_out,
    float* __restrict__ agg)
{
    __shared__ __bf16 in_t[TE][392];   // 384 used
    __shared__ __bf16 h1_t[TE][136];   // 128 used
    __shared__ int    src_s[TE], dst_s[TE];

    const int tid = threadIdx.x;
    const int e0g = blockIdx.x * TE;

    if (tid < TE) {
        src_s[tid] = edge_index[e0g + tid];            // edge_index[0] = src (j)
        dst_s[tid] = edge_index[NEDGES + e0g + tid];   // edge_index[1] = dst (i)
    }
    __syncthreads();

    for (int idx = tid; idx < TE * 96; idx += BLK) {
        const int e   = idx / 96;
        const int c   = idx % 96;
        const int seg = c >> 5;
        const int c4  = (c & 31) << 2;
        const float* p;
        if (seg == 0)      p = x + (size_t)dst_s[e] * D + c4;
        else if (seg == 1) p = x + (size_t)src_s[e] * D + c4;
        else               p = edge_attr + (size_t)(e0g + e) * D + c4;
        fx4 v = *(const fx4*)p;
        bf16x4 h;
        #pragma unroll
        for (int j = 0; j < 4; ++j) h[j] = (__bf16)v[j];
        *(bf16x4*)&in_t[e][seg * 128 + c4] = h;
    }
    __syncthreads();

    const int lane  = tid & 63;
    const int wid   = tid >> 6;
    const int wrow0 = wid << 4;
    const int c16   = lane & 15;
    const int kq    = lane >> 4;
    const int ks8   = kq << 3;

    // ---- GEMM1: [16,384] @ [384,128] per wave ----
    f32x4 acc[8];
    #pragma unroll
    for (int nf = 0; nf < 8; ++nf) acc[nf] = (f32x4){0.f, 0.f, 0.f, 0.f};

    #pragma unroll
    for (int k0 = 0; k0 < 3 * D; k0 += 32) {
        bf16x8 a = *(const bf16x8*)&in_t[wrow0 + c16][k0 + ks8];
        #pragma unroll
        for (int nf = 0; nf < 8; ++nf) {
            bf16x8 b = *(const bf16x8*)&W1T[(size_t)(nf * 16 + c16) * 384 + k0 + ks8];
            acc[nf] = __builtin_amdgcn_mfma_f32_16x16x32_bf16(a, b, acc[nf], 0, 0, 0);
        }
    }

    #pragma unroll
    for (int nf = 0; nf < 8; ++nf) {
        const float bb = b1[nf * 16 + c16];
        #pragma unroll
        for (int r = 0; r < 4; ++r) {
            float h = silu_f(acc[nf][r] + bb);
            h1_t[wrow0 + kq * 4 + r][nf * 16 + c16] = (__bf16)h;
        }
    }

    // ---- GEMM2: [16,128] @ [128,128] per wave ----
    f32x4 acc2[8];
    #pragma unroll
    for (int nf = 0; nf < 8; ++nf) acc2[nf] = (f32x4){0.f, 0.f, 0.f, 0.f};

    #pragma unroll
    for (int k0 = 0; k0 < D; k0 += 32) {
        bf16x8 a = *(const bf16x8*)&h1_t[wrow0 + c16][k0 + ks8];
        #pragma unroll
        for (int nf = 0; nf < 8; ++nf) {
            bf16x8 b = *(const bf16x8*)&W2T[(size_t)(nf * 16 + c16) * 128 + k0 + ks8];
            acc2[nf] = __builtin_amdgcn_mfma_f32_16x16x32_bf16(a, b, acc2[nf], 0, 0, 0);
        }
    }

    // ---- bias + LayerNorm + store (+ optional scatter-add) ----
    float b2v[8], gv[8], bvv[8];
    #pragma unroll
    for (int nf = 0; nf < 8; ++nf) {
        b2v[nf] = b2[nf * 16 + c16];
        gv[nf]  = lng[nf * 16 + c16];
        bvv[nf] = lnb[nf * 16 + c16];
    }

    float z[8][4];
    float s[4] = {0.f, 0.f, 0.f, 0.f}, q[4] = {0.f, 0.f, 0.f, 0.f};
    #pragma unroll
    for (int nf = 0; nf < 8; ++nf)
        #pragma unroll
        for (int r = 0; r < 4; ++r) {
            float zz = acc2[nf][r] + b2v[nf];
            z[nf][r] = zz;
            s[r] += zz;
            q[r] += zz * zz;
        }
    #pragma unroll
    for (int m = 1; m <= 8; m <<= 1)
        #pragma unroll
        for (int r = 0; r < 4; ++r) {
            s[r] += __shfl_xor(s[r], m, 64);
            q[r] += __shfl_xor(q[r], m, 64);
        }
    float mu[4], rstd[4];
    #pragma unroll
    for (int r = 0; r < 4; ++r) {
        mu[r] = s[r] * (1.0f / 128.0f);
        float var = q[r] * (1.0f / 128.0f) - mu[r] * mu[r];
        rstd[r] = rsqrtf(var + LN_EPS);
    }

    #pragma unroll
    for (int r = 0; r < 4; ++r) {
        const int row = wrow0 + kq * 4 + r;
        const size_t erow = (size_t)(e0g + row) * D;
        #pragma unroll
        for (int nf = 0; nf < 8; ++nf) {
            const int col = nf * 16 + c16;
            float o = (z[nf][r] - mu[r]) * rstd[r] * gv[nf] + bvv[nf];
            edges_out[erow + col] = o;
            if constexpr (ATOMIC) {
                atomicAdd(agg + (size_t)dst_s[row] * D + col, o);
            }
        }
    }
}

// ---------------------------------------------------------------------------
// Node kernel (bf16 MFMA): 64 nodes/block; in = [x, agg] (256)
// CSR=true: aggregate edges_new rows via CSR gather (no atomics anywhere).
// CSR=false: read pre-accumulated agg buffer.
// ---------------------------------------------------------------------------
template<bool CSR>
__global__ __launch_bounds__(BLK) void node_kernel(
    const float* __restrict__ x,
    const float* __restrict__ agg,        // CSR=false
    const float* __restrict__ edges_new,  // CSR=true
    const int*   __restrict__ offs,       // CSR=true
    const int*   __restrict__ elist,      // CSR=true
    const __bf16* __restrict__ W1T,       // [128][256]
    const float* __restrict__ b1,
    const __bf16* __restrict__ W2T,       // [128][128]
    const float* __restrict__ b2,
    const float* __restrict__ lng, const float* __restrict__ lnb,
    float* __restrict__ nodes_out)
{
    __shared__ __bf16 in_t[TE][264];   // 256 used
    __shared__ __bf16 h1_t[TE][136];

    const int tid = threadIdx.x;
    const int r0g = blockIdx.x * TE;

    // seg 0: x rows
    for (int idx = tid; idx < TE * 32; idx += BLK) {
        const int e   = idx >> 5;
        const int c4  = (idx & 31) << 2;
        const int row = r0g + e;
        fx4 v = {0.f, 0.f, 0.f, 0.f};
        if (row < NNODES) v = *(const fx4*)&x[(size_t)row * D + c4];
        bf16x4 h;
        #pragma unroll
        for (int j = 0; j < 4; ++j) h[j] = (__bf16)v[j];
        *(bf16x4*)&in_t[e][c4] = h;
    }
    // seg 1: aggregated messages
    for (int idx = tid; idx < TE * 32; idx += BLK) {
        const int e   = idx >> 5;
        const int c4  = (idx & 31) << 2;
        const int row = r0g + e;
        fx4 v = {0.f, 0.f, 0.f, 0.f};
        if (row < NNODES) {
            if constexpr (CSR) {
                const int p0 = offs[row], p1 = offs[row + 1];
                for (int p = p0; p < p1; ++p) {
                    const int eid = elist[p];
                    fx4 ev = *(const fx4*)&edges_new[(size_t)eid * D + c4];
                    #pragma unroll
                    for (int j = 0; j < 4; ++j) v[j] += ev[j];
                }
            } else {
                v = *(const fx4*)&agg[(size_t)row * D + c4];
            }
        }
        bf16x4 h;
        #pragma unroll
        for (int j = 0; j < 4; ++j) h[j] = (__bf16)v[j];
        *(bf16x4*)&in_t[e][128 + c4] = h;
    }
    __syncthreads();

    const int lane  = tid & 63;
    const int wid   = tid >> 6;
    const int wrow0 = wid << 4;
    const int c16   = lane & 15;
    const int kq    = lane >> 4;
    const int ks8   = kq << 3;

    // ---- GEMM1: [16,256] @ [256,128] ----
    f32x4 acc[8];
    #pragma unroll
    for (int nf = 0; nf < 8; ++nf) acc[nf] = (f32x4){0.f, 0.f, 0.f, 0.f};

    #pragma unroll
    for (int k0 = 0; k0 < 2 * D; k0 += 32) {
        bf16x8 a = *(const bf16x8*)&in_t[wrow0 + c16][k0 + ks8];
        #pragma unroll
        for (int nf = 0; nf < 8; ++nf) {
            bf16x8 b = *(const bf16x8*)&W1T[(size_t)(nf * 16 + c16) * 256 + k0 + ks8];
            acc[nf] = __builtin_amdgcn_mfma_f32_16x16x32_bf16(a, b, acc[nf], 0, 0, 0);
        }
    }

    #pragma unroll
    for (int nf = 0; nf < 8; ++nf) {
        const float bb = b1[nf * 16 + c16];
        #pragma unroll
        for (int r = 0; r < 4; ++r) {
            float h = silu_f(acc[nf][r] + bb);
            h1_t[wrow0 + kq * 4 + r][nf * 16 + c16] = (__bf16)h;
        }
    }

    // ---- GEMM2 ----
    f32x4 acc2[8];
    #pragma unroll
    for (int nf = 0; nf < 8; ++nf) acc2[nf] = (f32x4){0.f, 0.f, 0.f, 0.f};

    #pragma unroll
    for (int k0 = 0; k0 < D; k0 += 32) {
        bf16x8 a = *(const bf16x8*)&h1_t[wrow0 + c16][k0 + ks8];
        #pragma unroll
        for (int nf = 0; nf < 8; ++nf) {
            bf16x8 b = *(const bf16x8*)&W2T[(size_t)(nf * 16 + c16) * 128 + k0 + ks8];
            acc2[nf] = __builtin_amdgcn_mfma_f32_16x16x32_bf16(a, b, acc2[nf], 0, 0, 0);
        }
    }

    // ---- bias + LN + residual + store ----
    float b2v[8], gv[8], bvv[8];
    #pragma unroll
    for (int nf = 0; nf < 8; ++nf) {
        b2v[nf] = b2[nf * 16 + c16];
        gv[nf]  = lng[nf * 16 + c16];
        bvv[nf] = lnb[nf * 16 + c16];
    }

    float z[8][4];
    float s[4] = {0.f, 0.f, 0.f, 0.f}, q[4] = {0.f, 0.f, 0.f, 0.f};
    #pragma unroll
    for (int nf = 0; nf < 8; ++nf)
        #pragma unroll
        for (int r = 0; r < 4; ++r) {
            float zz = acc2[nf][r] + b2v[nf];
            z[nf][r] = zz;
            s[r] += zz;
            q[r] += zz * zz;
        }
    #pragma unroll
    for (int m = 1; m <= 8; m <<= 1)
        #pragma unroll
        for (int r = 0; r < 4; ++r) {
            s[r] += __shfl_xor(s[r], m, 64);
            q[r] += __shfl_xor(q[r], m, 64);
        }
    float mu[4], rstd[4];
    #pragma unroll
    for (int r = 0; r < 4; ++r) {
        mu[r] = s[r] * (1.0f / 128.0f);
        float var = q[r] * (1.0f / 128.0f) - mu[r] * mu[r];
        rstd[r] = rsqrtf(var + LN_EPS);
    }

    #pragma unroll
    for (int r = 0; r < 4; ++r) {
        const int row = r0g + wrow0 + kq * 4 + r;
        if (row >= NNODES) continue;
        const size_t orow = (size_t)row * D;
        #pragma unroll
        for (int nf = 0; nf < 8; ++nf) {
            const int col = nf * 16 + c16;
            float o = (z[nf][r] - mu[r]) * rstd[r] * gv[nf] + bvv[nf] + x[orow + col];
            nodes_out[orow + col] = o;
        }
    }
}

extern "C" void kernel_launch(void* const* d_in, const int* in_sizes, int n_in,
                              void* d_out, int out_size, void* d_ws, size_t ws_size,
                              hipStream_t stream) {
    (void)in_sizes; (void)n_in; (void)out_size;

    const float* x         = (const float*)d_in[0];
    const float* edge_attr = (const float*)d_in[1];
    const int*   edge_idx  = (const int*)  d_in[2];
    const float* eW1 = (const float*)d_in[3];
    const float* eb1 = (const float*)d_in[4];
    const float* eW2 = (const float*)d_in[5];
    const float* eb2 = (const float*)d_in[6];
    const float* elg = (const float*)d_in[7];
    const float* elb = (const float*)d_in[8];
    const float* nW1 = (const float*)d_in[9];
    const float* nb1 = (const float*)d_in[10];
    const float* nW2 = (const float*)d_in[11];
    const float* nb2 = (const float*)d_in[12];
    const float* nlg = (const float*)d_in[13];
    const float* nlb = (const float*)d_in[14];

    float* out       = (float*)d_out;
    float* nodes_out = out;
    float* edges_out = out + (size_t)NNODES * D;

    char*   wsb = (char*)d_ws;
    __bf16* ws  = (__bf16*)d_ws;

    prep_weights<<<(WS_ELEMS + 255) / 256, 256, 0, stream>>>(eW1, eW2, nW1, nW2, ws);

    if (ws_size >= (size_t)WS_NEED) {
        // ---- CSR path: no fp32 atomics anywhere ----
        int* counts = (int*)(wsb + COUNTS_OFF);
        int* offs   = (int*)(wsb + OFFS_OFF);
        int* curs   = (int*)(wsb + CURS_OFF);
        int* elist  = (int*)(wsb + ELIST_OFF);

        hipMemsetAsync(counts, 0, NNODES * sizeof(int), stream);
        hist_kernel<<<(NEDGES + 255) / 256, 256, 0, stream>>>(edge_idx, counts);
        scan_kernel<<<1, 256, 0, stream>>>(counts, offs, curs);
        scatter_kernel<<<(NEDGES + 255) / 256, 256, 0, stream>>>(edge_idx, curs, elist);

        edge_kernel<false><<<NEDGES / TE, BLK, 0, stream>>>(
            x, edge_attr, edge_idx,
            ws + EW1T_OFF, eb1, ws + EW2T_OFF, eb2, elg, elb,
            edges_out, nullptr);

        node_kernel<true><<<(NNODES + TE - 1) / TE, BLK, 0, stream>>>(
            x, nullptr, edges_out, offs, elist,
            ws + NW1T_OFF, nb1, ws + NW2T_OFF, nb2, nlg, nlb,
            nodes_out);
    } else {
        // ---- fallback: atomic aggregation into nodes_out ----
        hipMemsetAsync(nodes_out, 0, (size_t)NNODES * D * sizeof(float), stream);

        edge_kernel<true><<<NEDGES / TE, BLK, 0, stream>>>(
            x, edge_attr, edge_idx,
            ws + EW1T_OFF, eb1, ws + EW2T_OFF, eb2, elg, elb,
            edges_out, nodes_out);

        node_kernel<false><<<(NNODES + TE - 1) / TE, BLK, 0, stream>>>(
            x, nodes_out, nullptr, nullptr, nullptr,
            ws + NW1T_OFF, nb1, ws + NW2T_OFF, nb2, nlg, nlb,
            nodes_out);
    }
}

// Round 4
// 441.324 us; speedup vs baseline: 2.7344x; 2.7344x over previous
//
#include <hip/hip_runtime.h>

#define D       128
#define NNODES  50000
#define NEDGES  600000
#define TE      64
#define BLK     256
#define LN_EPS  1e-5f

typedef float  fx4    __attribute__((ext_vector_type(4)));
typedef float  f32x4  __attribute__((ext_vector_type(4)));
typedef __bf16 bf16x4 __attribute__((ext_vector_type(4)));
typedef __bf16 bf16x8 __attribute__((ext_vector_type(8)));

// ---- d_ws layout (bf16 elements) ----
// Fragment-major weights: frag[kstep][nf][lane(64)][8], 512 bf16 per frag.
#define EW1F_OFF 0                         // K=384: 12 ksteps * 8 nf
#define EW2F_OFF (128 * 384)               // K=128:  4 ksteps * 8 nf
#define NW1F_OFF (EW2F_OFF + 128 * 128)    // K=256:  8 ksteps * 8 nf
#define NW2F_OFF (NW1F_OFF + 128 * 256)    // K=128
#define WS_ELEMS (NW2F_OFF + 128 * 128)    // 114688 bf16

__device__ __forceinline__ float silu_f(float z) {
    return z * (1.0f / (1.0f + __expf(-z)));
}

// ---------------------------------------------------------------------------
// Weight prep: f32 [K][128] -> bf16 fragment-major.
// frag f = ks*8+nf ; lane l ; elem j  maps to  n = nf*16+(l&15),
// k = ks*32 + (l>>4)*8 + j.  Stored at  base + f*512 + l*8 + j.
// ---------------------------------------------------------------------------
__global__ __launch_bounds__(256) void prep_weights(
    const float* __restrict__ eW1, const float* __restrict__ eW2,
    const float* __restrict__ nW1, const float* __restrict__ nW2,
    __bf16* __restrict__ ws)
{
    int idx = blockIdx.x * 256 + threadIdx.x;
    if (idx >= WS_ELEMS) return;
    const float* src;
    int local;
    if (idx < EW2F_OFF)      { src = eW1; local = idx; }
    else if (idx < NW1F_OFF) { src = eW2; local = idx - EW2F_OFF; }
    else if (idx < NW2F_OFF) { src = nW1; local = idx - NW1F_OFF; }
    else                     { src = nW2; local = idx - NW2F_OFF; }
    const int f   = local >> 9;          // frag index
    const int rem = local & 511;
    const int l   = rem >> 3;            // lane
    const int j   = rem & 7;             // elem
    const int ks  = f >> 3;
    const int nf  = f & 7;
    const int n   = (nf << 4) + (l & 15);
    const int k   = (ks << 5) + ((l >> 4) << 3) + j;
    ws[idx] = (__bf16)src[(size_t)k * D + n];
}

// ---------------------------------------------------------------------------
// Edge kernel (bf16 MFMA): 64 edges/block, 4 waves, 16 rows each.
// W fragments coalesced from global; h1 tile aliased into in_t (wave-private).
// ---------------------------------------------------------------------------
__global__ __launch_bounds__(BLK) void edge_kernel(
    const float* __restrict__ x,
    const float* __restrict__ edge_attr,
    const int*   __restrict__ edge_index,
    const __bf16* __restrict__ W1f,
    const float* __restrict__ b1,
    const __bf16* __restrict__ W2f,
    const float* __restrict__ b2,
    const float* __restrict__ lng, const float* __restrict__ lnb,
    float* __restrict__ edges_out,
    float* __restrict__ agg)
{
    __shared__ __bf16 in_t[TE][392];   // 384 used; h1 aliases cols 0..127 later
    __shared__ int    src_s[TE], dst_s[TE];

    const int tid = threadIdx.x;
    const int e0g = blockIdx.x * TE;

    if (tid < TE) {
        src_s[tid] = edge_index[e0g + tid];            // edge_index[0] = src (j)
        dst_s[tid] = edge_index[NEDGES + e0g + tid];   // edge_index[1] = dst (i)
    }
    __syncthreads();

    // stage: 3 segments x (64 rows x 32 float4), shift-only indexing
    #pragma unroll
    for (int it = 0; it < 8; ++it) {
        const int idx = tid + it * BLK;
        const int e   = idx >> 5;
        const int c4  = (idx & 31) << 2;
        fx4 v = *(const fx4*)&x[(size_t)dst_s[e] * D + c4];
        bf16x4 h;
        #pragma unroll
        for (int j = 0; j < 4; ++j) h[j] = (__bf16)v[j];
        *(bf16x4*)&in_t[e][c4] = h;
    }
    #pragma unroll
    for (int it = 0; it < 8; ++it) {
        const int idx = tid + it * BLK;
        const int e   = idx >> 5;
        const int c4  = (idx & 31) << 2;
        fx4 v = *(const fx4*)&x[(size_t)src_s[e] * D + c4];
        bf16x4 h;
        #pragma unroll
        for (int j = 0; j < 4; ++j) h[j] = (__bf16)v[j];
        *(bf16x4*)&in_t[e][128 + c4] = h;
    }
    #pragma unroll
    for (int it = 0; it < 8; ++it) {
        const int idx = tid + it * BLK;
        const int e   = idx >> 5;
        const int c4  = (idx & 31) << 2;
        fx4 v = *(const fx4*)&edge_attr[(size_t)(e0g + e) * D + c4];
        bf16x4 h;
        #pragma unroll
        for (int j = 0; j < 4; ++j) h[j] = (__bf16)v[j];
        *(bf16x4*)&in_t[e][256 + c4] = h;
    }
    __syncthreads();

    const int lane  = tid & 63;
    const int wid   = tid >> 6;
    const int wrow0 = wid << 4;
    const int c16   = lane & 15;
    const int kq    = lane >> 4;
    const int ks8   = kq << 3;
    const int lo8   = lane << 3;       // fragment lane offset (bf16 elems)

    // ---- GEMM1: [16,384] @ [384,128] per wave ----
    f32x4 acc[8];
    #pragma unroll
    for (int nf = 0; nf < 8; ++nf) acc[nf] = (f32x4){0.f, 0.f, 0.f, 0.f};

    #pragma unroll
    for (int ks = 0; ks < 12; ++ks) {
        bf16x8 a = *(const bf16x8*)&in_t[wrow0 + c16][(ks << 5) + ks8];
        const __bf16* wp = W1f + ((size_t)(ks << 3) << 9) + lo8;
        #pragma unroll
        for (int nf = 0; nf < 8; ++nf) {
            bf16x8 b = *(const bf16x8*)(wp + (nf << 9));
            acc[nf] = __builtin_amdgcn_mfma_f32_16x16x32_bf16(a, b, acc[nf], 0, 0, 0);
        }
    }

    // SiLU + bias -> h1 aliased into in_t cols 0..127 (wave-private rows;
    // per-wave in-order LDS makes read-before-write safe without a barrier)
    #pragma unroll
    for (int nf = 0; nf < 8; ++nf) {
        const float bb = b1[nf * 16 + c16];
        #pragma unroll
        for (int r = 0; r < 4; ++r) {
            float h = silu_f(acc[nf][r] + bb);
            in_t[wrow0 + kq * 4 + r][nf * 16 + c16] = (__bf16)h;
        }
    }

    // ---- GEMM2: [16,128] @ [128,128] per wave ----
    f32x4 acc2[8];
    #pragma unroll
    for (int nf = 0; nf < 8; ++nf) acc2[nf] = (f32x4){0.f, 0.f, 0.f, 0.f};

    #pragma unroll
    for (int ks = 0; ks < 4; ++ks) {
        bf16x8 a = *(const bf16x8*)&in_t[wrow0 + c16][(ks << 5) + ks8];
        const __bf16* wp = W2f + ((size_t)(ks << 3) << 9) + lo8;
        #pragma unroll
        for (int nf = 0; nf < 8; ++nf) {
            bf16x8 b = *(const bf16x8*)(wp + (nf << 9));
            acc2[nf] = __builtin_amdgcn_mfma_f32_16x16x32_bf16(a, b, acc2[nf], 0, 0, 0);
        }
    }

    // ---- bias + LayerNorm + store + scatter-add ----
    float b2v[8], gv[8], bvv[8];
    #pragma unroll
    for (int nf = 0; nf < 8; ++nf) {
        b2v[nf] = b2[nf * 16 + c16];
        gv[nf]  = lng[nf * 16 + c16];
        bvv[nf] = lnb[nf * 16 + c16];
    }

    float z[8][4];
    float s[4] = {0.f, 0.f, 0.f, 0.f}, q[4] = {0.f, 0.f, 0.f, 0.f};
    #pragma unroll
    for (int nf = 0; nf < 8; ++nf)
        #pragma unroll
        for (int r = 0; r < 4; ++r) {
            float zz = acc2[nf][r] + b2v[nf];
            z[nf][r] = zz;
            s[r] += zz;
            q[r] += zz * zz;
        }
    #pragma unroll
    for (int m = 1; m <= 8; m <<= 1)
        #pragma unroll
        for (int r = 0; r < 4; ++r) {
            s[r] += __shfl_xor(s[r], m, 64);
            q[r] += __shfl_xor(q[r], m, 64);
        }
    float mu[4], rstd[4];
    #pragma unroll
    for (int r = 0; r < 4; ++r) {
        mu[r] = s[r] * (1.0f / 128.0f);
        float var = q[r] * (1.0f / 128.0f) - mu[r] * mu[r];
        rstd[r] = rsqrtf(var + LN_EPS);
    }

    #pragma unroll
    for (int r = 0; r < 4; ++r) {
        const int row = wrow0 + kq * 4 + r;
        const size_t erow = (size_t)(e0g + row) * D;
        float* ap = agg + (size_t)dst_s[row] * D;
        #pragma unroll
        for (int nf = 0; nf < 8; ++nf) {
            const int col = nf * 16 + c16;
            float o = (z[nf][r] - mu[r]) * rstd[r] * gv[nf] + bvv[nf];
            edges_out[erow + col] = o;
            atomicAdd(ap + col, o);
        }
    }
}

// ---------------------------------------------------------------------------
// Node kernel (bf16 MFMA): 64 nodes/block; in = [x, agg] (256)
// ---------------------------------------------------------------------------
__global__ __launch_bounds__(BLK) void node_kernel(
    const float* __restrict__ x,
    const float* __restrict__ agg,
    const __bf16* __restrict__ W1f,
    const float* __restrict__ b1,
    const __bf16* __restrict__ W2f,
    const float* __restrict__ b2,
    const float* __restrict__ lng, const float* __restrict__ lnb,
    float* __restrict__ nodes_out)
{
    __shared__ __bf16 in_t[TE][264];   // 256 used; h1 aliases cols 0..127

    const int tid = threadIdx.x;
    const int r0g = blockIdx.x * TE;

    #pragma unroll
    for (int it = 0; it < 8; ++it) {
        const int idx = tid + it * BLK;
        const int e   = idx >> 5;
        const int c4  = (idx & 31) << 2;
        const int row = r0g + e;
        fx4 v = {0.f, 0.f, 0.f, 0.f};
        if (row < NNODES) v = *(const fx4*)&x[(size_t)row * D + c4];
        bf16x4 h;
        #pragma unroll
        for (int j = 0; j < 4; ++j) h[j] = (__bf16)v[j];
        *(bf16x4*)&in_t[e][c4] = h;
    }
    #pragma unroll
    for (int it = 0; it < 8; ++it) {
        const int idx = tid + it * BLK;
        const int e   = idx >> 5;
        const int c4  = (idx & 31) << 2;
        const int row = r0g + e;
        fx4 v = {0.f, 0.f, 0.f, 0.f};
        if (row < NNODES) v = *(const fx4*)&agg[(size_t)row * D + c4];
        bf16x4 h;
        #pragma unroll
        for (int j = 0; j < 4; ++j) h[j] = (__bf16)v[j];
        *(bf16x4*)&in_t[e][128 + c4] = h;
    }
    __syncthreads();

    const int lane  = tid & 63;
    const int wid   = tid >> 6;
    const int wrow0 = wid << 4;
    const int c16   = lane & 15;
    const int kq    = lane >> 4;
    const int ks8   = kq << 3;
    const int lo8   = lane << 3;

    // ---- GEMM1: [16,256] @ [256,128] ----
    f32x4 acc[8];
    #pragma unroll
    for (int nf = 0; nf < 8; ++nf) acc[nf] = (f32x4){0.f, 0.f, 0.f, 0.f};

    #pragma unroll
    for (int ks = 0; ks < 8; ++ks) {
        bf16x8 a = *(const bf16x8*)&in_t[wrow0 + c16][(ks << 5) + ks8];
        const __bf16* wp = W1f + ((size_t)(ks << 3) << 9) + lo8;
        #pragma unroll
        for (int nf = 0; nf < 8; ++nf) {
            bf16x8 b = *(const bf16x8*)(wp + (nf << 9));
            acc[nf] = __builtin_amdgcn_mfma_f32_16x16x32_bf16(a, b, acc[nf], 0, 0, 0);
        }
    }

    #pragma unroll
    for (int nf = 0; nf < 8; ++nf) {
        const float bb = b1[nf * 16 + c16];
        #pragma unroll
        for (int r = 0; r < 4; ++r) {
            float h = silu_f(acc[nf][r] + bb);
            in_t[wrow0 + kq * 4 + r][nf * 16 + c16] = (__bf16)h;
        }
    }

    // ---- GEMM2 ----
    f32x4 acc2[8];
    #pragma unroll
    for (int nf = 0; nf < 8; ++nf) acc2[nf] = (f32x4){0.f, 0.f, 0.f, 0.f};

    #pragma unroll
    for (int ks = 0; ks < 4; ++ks) {
        bf16x8 a = *(const bf16x8*)&in_t[wrow0 + c16][(ks << 5) + ks8];
        const __bf16* wp = W2f + ((size_t)(ks << 3) << 9) + lo8;
        #pragma unroll
        for (int nf = 0; nf < 8; ++nf) {
            bf16x8 b = *(const bf16x8*)(wp + (nf << 9));
            acc2[nf] = __builtin_amdgcn_mfma_f32_16x16x32_bf16(a, b, acc2[nf], 0, 0, 0);
        }
    }

    // ---- bias + LN + residual + store ----
    float b2v[8], gv[8], bvv[8];
    #pragma unroll
    for (int nf = 0; nf < 8; ++nf) {
        b2v[nf] = b2[nf * 16 + c16];
        gv[nf]  = lng[nf * 16 + c16];
        bvv[nf] = lnb[nf * 16 + c16];
    }

    float z[8][4];
    float s[4] = {0.f, 0.f, 0.f, 0.f}, q[4] = {0.f, 0.f, 0.f, 0.f};
    #pragma unroll
    for (int nf = 0; nf < 8; ++nf)
        #pragma unroll
        for (int r = 0; r < 4; ++r) {
            float zz = acc2[nf][r] + b2v[nf];
            z[nf][r] = zz;
            s[r] += zz;
            q[r] += zz * zz;
        }
    #pragma unroll
    for (int m = 1; m <= 8; m <<= 1)
        #pragma unroll
        for (int r = 0; r < 4; ++r) {
            s[r] += __shfl_xor(s[r], m, 64);
            q[r] += __shfl_xor(q[r], m, 64);
        }
    float mu[4], rstd[4];
    #pragma unroll
    for (int r = 0; r < 4; ++r) {
        mu[r] = s[r] * (1.0f / 128.0f);
        float var = q[r] * (1.0f / 128.0f) - mu[r] * mu[r];
        rstd[r] = rsqrtf(var + LN_EPS);
    }

    #pragma unroll
    for (int r = 0; r < 4; ++r) {
        const int row = r0g + wrow0 + kq * 4 + r;
        if (row >= NNODES) continue;
        const size_t orow = (size_t)row * D;
        #pragma unroll
        for (int nf = 0; nf < 8; ++nf) {
            const int col = nf * 16 + c16;
            float o = (z[nf][r] - mu[r]) * rstd[r] * gv[nf] + bvv[nf] + x[orow + col];
            nodes_out[orow + col] = o;
        }
    }
}

extern "C" void kernel_launch(void* const* d_in, const int* in_sizes, int n_in,
                              void* d_out, int out_size, void* d_ws, size_t ws_size,
                              hipStream_t stream) {
    (void)in_sizes; (void)n_in; (void)ws_size; (void)out_size;

    const float* x         = (const float*)d_in[0];
    const float* edge_attr = (const float*)d_in[1];
    const int*   edge_idx  = (const int*)  d_in[2];
    const float* eW1 = (const float*)d_in[3];
    const float* eb1 = (const float*)d_in[4];
    const float* eW2 = (const float*)d_in[5];
    const float* eb2 = (const float*)d_in[6];
    const float* elg = (const float*)d_in[7];
    const float* elb = (const float*)d_in[8];
    const float* nW1 = (const float*)d_in[9];
    const float* nb1 = (const float*)d_in[10];
    const float* nW2 = (const float*)d_in[11];
    const float* nb2 = (const float*)d_in[12];
    const float* nlg = (const float*)d_in[13];
    const float* nlb = (const float*)d_in[14];

    float* out       = (float*)d_out;
    float* nodes_out = out;                        // doubles as agg accumulator
    float* edges_out = out + (size_t)NNODES * D;

    __bf16* ws = (__bf16*)d_ws;

    prep_weights<<<(WS_ELEMS + 255) / 256, 256, 0, stream>>>(eW1, eW2, nW1, nW2, ws);

    hipMemsetAsync(nodes_out, 0, (size_t)NNODES * D * sizeof(float), stream);

    edge_kernel<<<NEDGES / TE, BLK, 0, stream>>>(
        x, edge_attr, edge_idx,
        ws + EW1F_OFF, eb1, ws + EW2F_OFF, eb2, elg, elb,
        edges_out, nodes_out);

    node_kernel<<<(NNODES + TE - 1) / TE, BLK, 0, stream>>>(
        x, nodes_out,
        ws + NW1F_OFF, nb1, ws + NW2F_OFF, nb2, nlg, nlb,
        nodes_out);
}